// Round 1
// baseline (3185.682 us; speedup 1.0000x reference)
//
#include <hip/hip_runtime.h>
#include <hip/hip_bf16.h>

// Problem constants
#define NROWS 2048
#define HDIM  4096
#define VDIM  32000

typedef __attribute__((ext_vector_type(8))) __bf16 bf16x8;
typedef __attribute__((ext_vector_type(4))) float floatx4;
typedef __attribute__((ext_vector_type(8))) unsigned short ushort8;
typedef __attribute__((ext_vector_type(4))) unsigned short ushort4v;

__device__ __forceinline__ unsigned short f2bf(float x) {
  unsigned u = __builtin_bit_cast(unsigned, x);
  return (unsigned short)((u + 0x7fffu + ((u >> 16) & 1u)) >> 16);  // RNE
}
__device__ __forceinline__ float bf2f(unsigned short h) {
  return __builtin_bit_cast(float, (unsigned)h << 16);
}

__device__ __forceinline__ void ld_lds16(const void* g, void* l) {
  __builtin_amdgcn_global_load_lds(
      (const __attribute__((address_space(1))) void*)g,
      (__attribute__((address_space(3))) void*)l, 16, 0, 0);
}

// ---------------------------------------------------------------------------
// fp32 -> bf16 cast, float4 in / ushort4 out
__global__ __launch_bounds__(256) void cvt_kernel(const float4* __restrict__ in,
                                                  ushort4v* __restrict__ out, int n4) {
  int i = blockIdx.x * 256 + threadIdx.x;
  if (i < n4) {
    float4 v = in[i];
    ushort4v o = {f2bf(v.x), f2bf(v.y), f2bf(v.z), f2bf(v.w)};
    out[i] = o;
  }
}

__global__ void zero_out(float* p) { p[0] = 0.0f; }

// ---------------------------------------------------------------------------
// C[m][v] = sum_k A[m][k] * B[v][k] + bias[v], stored as bf16
// m97 structure: 128x128 tile, BK=32, 256 threads (4 waves, 2x2 wave grid,
// 4x4 fragments of 16x16x32 per wave), global_load_lds width=16 staging.
__global__ __launch_bounds__(256, 2) void gemm_bt(const unsigned short* __restrict__ A,
                                                  const unsigned short* __restrict__ B,
                                                  const float* __restrict__ bias,
                                                  unsigned short* __restrict__ C) {
  __shared__ unsigned short lA[128 * 32];
  __shared__ unsigned short lB[128 * 32];
  const int t = threadIdx.x;
  const int wave = t >> 6;
  const int lane = t & 63;
  const int quad = lane >> 4;
  const int l16 = lane & 15;
  const int waveM = wave & 1;
  const int waveN = wave >> 1;
  const int m0 = blockIdx.y * 128;
  const int v0 = blockIdx.x * 128;

  // staging: inst i covers LDS bytes [i*4096 + t*16, +16) of the 128x32 bf16
  // tile (row-major, 64B rows) -> row = i*64 + t/4, kbyte = (t&3)*16
  const int srow = t >> 2;
  const int scolb = (t & 3) * 16;
  const char* gA0 = (const char*)(A + (size_t)(m0 + srow) * HDIM) + scolb;
  const char* gA1 = (const char*)(A + (size_t)(m0 + 64 + srow) * HDIM) + scolb;
  const char* gB0 = (const char*)(B + (size_t)(v0 + srow) * HDIM) + scolb;
  const char* gB1 = (const char*)(B + (size_t)(v0 + 64 + srow) * HDIM) + scolb;
  char* lA0 = (char*)lA + wave * 1024;           // wave-uniform LDS dst
  char* lA1 = (char*)lA + 4096 + wave * 1024;
  char* lB0 = (char*)lB + wave * 1024;
  char* lB1 = (char*)lB + 4096 + wave * 1024;

  floatx4 acc[4][4] = {};

  // fragment base: lane reads 8 contiguous bf16 at row (l16) of its subtile,
  // k-offset quad*8 (A-operand layout A[m=lane&15][k=quad*8+j]; B symmetric)
  const unsigned short* sAp = lA + (waveM * 64 + l16) * 32 + quad * 8;
  const unsigned short* sBp = lB + (waveN * 64 + l16) * 32 + quad * 8;

  for (int k = 0; k < HDIM; k += 32) {
    const size_t kb = (size_t)k * 2;
    ld_lds16(gA0 + kb, lA0);
    ld_lds16(gA1 + kb, lA1);
    ld_lds16(gB0 + kb, lB0);
    ld_lds16(gB1 + kb, lB1);
    __syncthreads();  // drains vmcnt: LDS tiles complete
    bf16x8 af[4], bfr[4];
#pragma unroll
    for (int i = 0; i < 4; i++) af[i] = *(const bf16x8*)(sAp + i * 16 * 32);
#pragma unroll
    for (int i = 0; i < 4; i++) bfr[i] = *(const bf16x8*)(sBp + i * 16 * 32);
#pragma unroll
    for (int fm = 0; fm < 4; fm++)
#pragma unroll
      for (int fn = 0; fn < 4; fn++)
        acc[fm][fn] =
            __builtin_amdgcn_mfma_f32_16x16x32_bf16(af[fm], bfr[fn], acc[fm][fn], 0, 0, 0);
    __syncthreads();  // all reads done before next overwrite
  }

  // epilogue: C/D layout col=lane&15, row=quad*4+reg
#pragma unroll
  for (int fn = 0; fn < 4; fn++) {
    const int colv = v0 + waveN * 64 + fn * 16 + l16;
    const float bv = bias[colv];
#pragma unroll
    for (int fm = 0; fm < 4; fm++) {
      const int rbase = m0 + waveM * 64 + fm * 16 + quad * 4;
#pragma unroll
      for (int r = 0; r < 4; r++) {
        C[(size_t)(rbase + r) * VDIM + colv] = f2bf(acc[fm][fn][r] + bv);
      }
    }
  }
}

// ---------------------------------------------------------------------------
// Per-row online max + sum-exp for both logit arrays. One block per row.
// Stores logZ = max + log(sumexp) for student (.x) and teacher (.y).
__global__ __launch_bounds__(256) void row_stats(const unsigned short* __restrict__ Ls,
                                                 const unsigned short* __restrict__ Lt,
                                                 float2* __restrict__ stats) {
  const int row = blockIdx.x;
  const unsigned short* ps = Ls + (size_t)row * VDIM;
  const unsigned short* pt = Lt + (size_t)row * VDIM;
  float ms = -1e30f, ss = 0.f, mt = -1e30f, st = 0.f;
  for (int c = threadIdx.x * 8; c < VDIM; c += 2048) {
    ushort8 a = *(const ushort8*)(ps + c);
    ushort8 b = *(const ushort8*)(pt + c);
    float xa[8], xb[8];
#pragma unroll
    for (int j = 0; j < 8; j++) { xa[j] = bf2f(a[j]); xb[j] = bf2f(b[j]); }
    float cma = xa[0], cmb = xb[0];
#pragma unroll
    for (int j = 1; j < 8; j++) { cma = fmaxf(cma, xa[j]); cmb = fmaxf(cmb, xb[j]); }
    float mna = fmaxf(ms, cma), mnb = fmaxf(mt, cmb);
    float ea = 0.f, eb = 0.f;
#pragma unroll
    for (int j = 0; j < 8; j++) { ea += __expf(xa[j] - mna); eb += __expf(xb[j] - mnb); }
    ss = ss * __expf(ms - mna) + ea; ms = mna;
    st = st * __expf(mt - mnb) + eb; mt = mnb;
  }
#pragma unroll
  for (int off = 32; off >= 1; off >>= 1) {
    float mo = __shfl_down(ms, off), so = __shfl_down(ss, off);
    float mn = fmaxf(ms, mo);
    ss = ss * __expf(ms - mn) + so * __expf(mo - mn); ms = mn;
    mo = __shfl_down(mt, off); so = __shfl_down(st, off);
    mn = fmaxf(mt, mo);
    st = st * __expf(mt - mn) + so * __expf(mo - mn); mt = mn;
  }
  __shared__ float4 wred[4];
  const int wv = threadIdx.x >> 6;
  if ((threadIdx.x & 63) == 0) wred[wv] = make_float4(ms, ss, mt, st);
  __syncthreads();
  if (threadIdx.x == 0) {
    float4 r0 = wred[0];
    float M1 = r0.x, S1 = r0.y, M2 = r0.z, S2 = r0.w;
    for (int w = 1; w < 4; w++) {
      float4 rw = wred[w];
      float mn = fmaxf(M1, rw.x);
      S1 = S1 * __expf(M1 - mn) + rw.y * __expf(rw.x - mn); M1 = mn;
      mn = fmaxf(M2, rw.z);
      S2 = S2 * __expf(M2 - mn) + rw.w * __expf(rw.z - mn); M2 = mn;
    }
    stats[row] = make_float2(M1 + __logf(S1), M2 + __logf(S2));
  }
}

// ---------------------------------------------------------------------------
// Elementwise generalized JSD (beta = 0.5), batchmean -> scalar
__global__ __launch_bounds__(256) void jsd_kernel(const unsigned short* __restrict__ Ls,
                                                  const unsigned short* __restrict__ Lt,
                                                  const float2* __restrict__ stats,
                                                  float* __restrict__ out) {
  const int row = blockIdx.y;
  const float2 z = stats[row];
  const int c = blockIdx.x * 2048 + threadIdx.x * 8;
  float local = 0.f;
  if (c < VDIM) {  // VDIM % 8 == 0, so in-bounds chunks are always full
    ushort8 a = *(const ushort8*)(Ls + (size_t)row * VDIM + c);
    ushort8 b = *(const ushort8*)(Lt + (size_t)row * VDIM + c);
#pragma unroll
    for (int j = 0; j < 8; j++) {
      float lq = bf2f(a[j]) - z.x;  // student log-softmax
      float lp = bf2f(b[j]) - z.y;  // teacher log-softmax
      float q = __expf(lq);
      float p = __expf(lp);
      float lm = __logf(0.5f * (p + q));
      local += 0.5f * (p * (lp - lm) + q * (lq - lm));
    }
  }
#pragma unroll
  for (int off = 32; off >= 1; off >>= 1) local += __shfl_down(local, off);
  __shared__ float wred[4];
  const int wv = threadIdx.x >> 6;
  if ((threadIdx.x & 63) == 0) wred[wv] = local;
  __syncthreads();
  if (threadIdx.x == 0) {
    float s = wred[0] + wred[1] + wred[2] + wred[3];
    atomicAdd(out, s * (1.0f / (float)NROWS));
  }
}

// ---------------------------------------------------------------------------
extern "C" void kernel_launch(void* const* d_in, const int* in_sizes, int n_in,
                              void* d_out, int out_size, void* d_ws, size_t ws_size,
                              hipStream_t stream) {
  const float* s_in = (const float*)d_in[0];
  const float* t_in = (const float*)d_in[1];
  const float* W_s = (const float*)d_in[2];
  const float* b_s = (const float*)d_in[3];
  const float* W_t = (const float*)d_in[4];
  const float* b_t = (const float*)d_in[5];
  float* out = (float*)d_out;

  // workspace layout (total 557,858,816 B):
  //   wsW   : shared bf16 W buffer (student then teacher)  262,144,000
  //   sA/tA : bf16 inputs                                 2x 16,777,216
  //   Lsb/Ltb: bf16 logits                               2x 131,072,000
  //   stats : per-row float2 logZ                              16,384
  char* ws = (char*)d_ws;
  unsigned short* wsW = (unsigned short*)(ws);
  unsigned short* sA = (unsigned short*)(ws + 262144000);
  unsigned short* tA = (unsigned short*)(ws + 278921216);
  unsigned short* Lsb = (unsigned short*)(ws + 295698432);
  unsigned short* Ltb = (unsigned short*)(ws + 426770432);
  float2* stats = (float2*)(ws + 557842432);

  zero_out<<<dim3(1), dim3(1), 0, stream>>>(out);

  cvt_kernel<<<dim3(8192), dim3(256), 0, stream>>>((const float4*)s_in, (ushort4v*)sA,
                                                   NROWS * HDIM / 4);
  cvt_kernel<<<dim3(8192), dim3(256), 0, stream>>>((const float4*)t_in, (ushort4v*)tA,
                                                   NROWS * HDIM / 4);

  cvt_kernel<<<dim3(128000), dim3(256), 0, stream>>>((const float4*)W_s, (ushort4v*)wsW,
                                                     VDIM * HDIM / 4);
  gemm_bt<<<dim3(VDIM / 128, NROWS / 128), dim3(256), 0, stream>>>(sA, wsW, b_s, Lsb);

  cvt_kernel<<<dim3(128000), dim3(256), 0, stream>>>((const float4*)W_t, (ushort4v*)wsW,
                                                     VDIM * HDIM / 4);
  gemm_bt<<<dim3(VDIM / 128, NROWS / 128), dim3(256), 0, stream>>>(tA, wsW, b_t, Ltb);

  row_stats<<<dim3(NROWS), dim3(256), 0, stream>>>(Lsb, Ltb, stats);
  jsd_kernel<<<dim3((VDIM + 2047) / 2048, NROWS), dim3(256), 0, stream>>>(Lsb, Ltb, stats, out);
}